// Round 10
// baseline (670.805 us; speedup 1.0000x reference)
//
#include <hip/hip_runtime.h>
#include <hip/hip_bf16.h>
#include <hip/hip_cooperative_groups.h>
#include <math.h>

namespace cg = cooperative_groups;

#define DIM 128
#define DFF 512
#define TTW 64
#define NPI 8
#define NTOK 9
#define TILE_H 16

typedef __attribute__((ext_vector_type(8))) short short8;
typedef __attribute__((ext_vector_type(4))) float float4v;

__device__ __forceinline__ float bf16lo_f32(unsigned u) {
    union { unsigned u; float f; } v; v.u = u << 16;
    return v.f;
}
__device__ __forceinline__ float bf16hi_f32(unsigned u) {
    union { unsigned u; float f; } v; v.u = u & 0xffff0000u;
    return v.f;
}
__device__ __forceinline__ unsigned pk_bf16(float a, float b) {  // -> a | b<<16
    __hip_bfloat162 h = __float22bfloat162_rn(float2{a, b});
    union { __hip_bfloat162 h; unsigned u; } cv; cv.h = h;
    return cv.u;
}

// ============ prep (fallback path): hf->bf16 + W1/W2 transposes ============
__global__ __launch_bounds__(256)
void prep_k(const float* __restrict__ hf, const float* __restrict__ W1,
            const float* __restrict__ W2,
            unsigned short* __restrict__ hf2, unsigned short* __restrict__ w1t,
            unsigned short* __restrict__ w2t,
            int n_hf, int B_HF)
{
    __shared__ float tile[32][33];
    const int b = blockIdx.x, t = threadIdx.x;
    if (b < B_HF) {
        int i = (b * 256 + t) * 8;
        if (i < n_hf) {
            float4v v0 = *(const float4v*)(hf + i);
            float4v v1 = *(const float4v*)(hf + i + 4);
            uint4 o;
            o.x = pk_bf16(v0[0], v0[1]);
            o.y = pk_bf16(v0[2], v0[3]);
            o.z = pk_bf16(v1[0], v1[1]);
            o.w = pk_bf16(v1[2], v1[3]);
            *(uint4*)(hf2 + i) = o;
        }
    } else if (b < B_HF + 64) {
        const int tb = b - B_HF;            // W1 [128][512] -> w1t bf16 [512][128]
        const int r0 = (tb & 3) * 32, c0 = (tb >> 2) * 32;
        const int ty = t >> 3, tx = t & 7;
        *(float4v*)&tile[ty][tx * 4] = *(const float4v*)(W1 + (r0 + ty) * DFF + c0 + tx * 4);
        __syncthreads();
        uint2 o;
        o.x = pk_bf16(tile[tx * 4 + 0][ty], tile[tx * 4 + 1][ty]);
        o.y = pk_bf16(tile[tx * 4 + 2][ty], tile[tx * 4 + 3][ty]);
        *(uint2*)(w1t + (c0 + ty) * DIM + r0 + tx * 4) = o;
    } else {
        const int tb = b - B_HF - 64;       // W2 [512][64] -> w2t bf16 [64][512]
        const int r0 = (tb & 15) * 32, c0 = (tb >> 4) * 32;
        const int ty = t >> 3, tx = t & 7;
        *(float4v*)&tile[ty][tx * 4] = *(const float4v*)(W2 + (r0 + ty) * TTW + c0 + tx * 4);
        __syncthreads();
        uint2 o;
        o.x = pk_bf16(tile[tx * 4 + 0][ty], tile[tx * 4 + 1][ty]);
        o.y = pk_bf16(tile[tx * 4 + 2][ty], tile[tx * 4 + 3][ty]);
        *(uint2*)(w2t + (c0 + ty) * DFF + r0 + tx * 4) = o;
    }
}

// ===== fused body: [COOP: prep + grid.sync] + persistent loop over 16-hop tiles =====
// __launch_bounds__(256,3): tighter bounds spill the fp32 accumulators
// (R7: WRITE_SIZE 37->214 MB). TILE_H=16 -> LDS ~17.2 KB, VGPR ~70.
template<bool COOP>
__global__ __launch_bounds__(256, 3)
void fused_t(const float* __restrict__ hf,
             const float* __restrict__ w_q,
             const int* __restrict__ pi,
             const int* __restrict__ stats,
             const int* __restrict__ po,
             const float* __restrict__ W1,
             const float* __restrict__ W2,
             const float* __restrict__ b1,
             const float* __restrict__ gamma,
             const float* __restrict__ beta,
             const float* __restrict__ b2,
             unsigned short* __restrict__ hf2,     // ws: bf16 node features
             unsigned short* __restrict__ w1t,     // ws: bf16 [512][128]
             unsigned short* __restrict__ w2t,     // ws: bf16 [64][512]
             float* __restrict__ out,
             int H, int ntiles, int n_hf)
{
    // Hsm[16][520] (16640 B). Apool[16][136] (4352 B) aliases its head: Apool is
    // dead after GEMM1 B-frag loads; Hsm is first written after the `part`
    // barrier. Phase-0 transpose tile (4224 B) also aliases (precedes grid.sync).
    __shared__ __align__(16) unsigned short Hsm[TILE_H][DFF + 8];
    __shared__ float part[16][4][2];                // [row][wave][sum,ssq]
    unsigned short (*Apool)[DIM + 8] = (unsigned short (*)[DIM + 8])&Hsm[0][0];
    float (*tile)[33] = (float (*)[33])&Hsm[0][0];

    const int t    = threadIdx.x;
    const int lane = t & 63;
    const int w    = t >> 6;
    const int row  = lane & 15;
    const int quad = lane >> 4;

    if constexpr (COOP) {
        // ---- Phase 0: weight/feature conversion (grid-strided / first 96 blocks) ----
        const int stride = gridDim.x * 256 * 8;
        for (int i = (blockIdx.x * 256 + t) * 8; i < n_hf; i += stride) {
            float4v v0 = *(const float4v*)(hf + i);
            float4v v1 = *(const float4v*)(hf + i + 4);
            uint4 o;
            o.x = pk_bf16(v0[0], v0[1]);
            o.y = pk_bf16(v0[2], v0[3]);
            o.z = pk_bf16(v1[0], v1[1]);
            o.w = pk_bf16(v1[2], v1[3]);
            *(uint4*)(hf2 + i) = o;
        }
        if (blockIdx.x < 64) {
            const int tb = blockIdx.x;          // W1 [128][512] -> w1t bf16 [512][128]
            const int r0 = (tb & 3) * 32, c0 = (tb >> 2) * 32;
            const int ty = t >> 3, tx = t & 7;
            *(float4v*)&tile[ty][tx * 4] = *(const float4v*)(W1 + (r0 + ty) * DFF + c0 + tx * 4);
            __syncthreads();
            uint2 o;
            o.x = pk_bf16(tile[tx * 4 + 0][ty], tile[tx * 4 + 1][ty]);
            o.y = pk_bf16(tile[tx * 4 + 2][ty], tile[tx * 4 + 3][ty]);
            *(uint2*)(w1t + (c0 + ty) * DIM + r0 + tx * 4) = o;
        } else if (blockIdx.x < 96) {
            const int tb = blockIdx.x - 64;     // W2 [512][64] -> w2t bf16 [64][512]
            const int r0 = (tb & 15) * 32, c0 = (tb >> 4) * 32;
            const int ty = t >> 3, tx = t & 7;
            *(float4v*)&tile[ty][tx * 4] = *(const float4v*)(W2 + (r0 + ty) * TTW + c0 + tx * 4);
            __syncthreads();
            uint2 o;
            o.x = pk_bf16(tile[tx * 4 + 0][ty], tile[tx * 4 + 1][ty]);
            o.y = pk_bf16(tile[tx * 4 + 2][ty], tile[tx * 4 + 3][ty]);
            *(uint2*)(w2t + (c0 + ty) * DFF + r0 + tx * 4) = o;
        }
        __threadfence();             // device-scope release: publish ws across XCDs
        cg::this_grid().sync();
        __syncthreads();             // re-converge before Apool writes (tile alias)
    }

    // ================= Main loop: blocks over 16-hop tiles =================
    for (int tilei = blockIdx.x; tilei < ntiles; tilei += gridDim.x) {
        const int hop0 = tilei * TILE_H;

        // -------- Phase 1: gather + masked attention pooling (32 lanes/hop) --------
        {
            const int g = t >> 5, l = t & 31;       // lane l owns dims 4l..4l+3
            const float4v wq4 = *(const float4v*)(w_q + l * 4);
            #pragma unroll
            for (int it = 0; it < 2; ++it) {
                const int hl = g + it * 8;
                const int hop = hop0 + hl;
                uint2 o = {0u, 0u};
                if (hop < H) {
                    int idx[NTOK]; bool val[NTOK];
                    int4 p0 = *(const int4*)(pi + hop * NPI);
                    int4 p1 = *(const int4*)(pi + hop * NPI + 4);
                    int4 s0 = *(const int4*)(stats + hop * NPI);
                    int4 s1 = *(const int4*)(stats + hop * NPI + 4);
                    idx[0]=p0.x; val[0]=s0.x != -1;
                    idx[1]=p0.y; val[1]=s0.y != -1;
                    idx[2]=p0.z; val[2]=s0.z != -1;
                    idx[3]=p0.w; val[3]=s0.w != -1;
                    idx[4]=p1.x; val[4]=s1.x != -1;
                    idx[5]=p1.y; val[5]=s1.y != -1;
                    idx[6]=p1.z; val[6]=s1.z != -1;
                    idx[7]=p1.w; val[7]=s1.w != -1;
                    idx[8]=po[hop]; val[8]=true;
                    uint2 tu[NTOK];
                    #pragma unroll
                    for (int p = 0; p < NTOK; ++p)
                        tu[p] = *(const uint2*)(hf2 + (size_t)idx[p] * DIM + l * 4);
                    float tok[NTOK][4];
                    #pragma unroll
                    for (int p = 0; p < NTOK; ++p) {
                        tok[p][0] = bf16lo_f32(tu[p].x);
                        tok[p][1] = bf16hi_f32(tu[p].x);
                        tok[p][2] = bf16lo_f32(tu[p].y);
                        tok[p][3] = bf16hi_f32(tu[p].y);
                    }
                    float sc[NTOK];
                    #pragma unroll
                    for (int p = 0; p < NTOK; ++p)
                        sc[p] = tok[p][0]*wq4[0] + tok[p][1]*wq4[1]
                              + tok[p][2]*wq4[2] + tok[p][3]*wq4[3];
                    #pragma unroll
                    for (int m = 1; m < 32; m <<= 1) {
                        #pragma unroll
                        for (int p = 0; p < NTOK; ++p) sc[p] += __shfl_xor(sc[p], m);
                    }
                    const float isd = 0.08838834764831845f;   // 1/sqrt(128)
                    float mx = -1e30f;
                    #pragma unroll
                    for (int p = 0; p < NTOK; ++p) {
                        sc[p] = val[p] ? sc[p] * isd : -1e30f;
                        mx = fmaxf(mx, sc[p]);
                    }
                    float se = 0.f;
                    #pragma unroll
                    for (int p = 0; p < NTOK; ++p) { sc[p] = __expf(sc[p] - mx); se += sc[p]; }
                    const float inv = 1.f / se;
                    float a0=0.f, a1=0.f, a2=0.f, a3=0.f;
                    #pragma unroll
                    for (int p = 0; p < NTOK; ++p) {
                        float a = sc[p] * inv;
                        a0 += a * tok[p][0]; a1 += a * tok[p][1];
                        a2 += a * tok[p][2]; a3 += a * tok[p][3];
                    }
                    o.x = pk_bf16(a0, a1);
                    o.y = pk_bf16(a2, a3);
                }
                *(uint2*)&Apool[hl][l * 4] = o;
            }
        }
        __syncthreads();

        // -------- GEMM1: A=W1T rows (out-dims), B=Apool^T (16 hops) --------
        float4v acc[8];
        #pragma unroll
        for (int mt = 0; mt < 8; ++mt) acc[mt] = (float4v){0.f, 0.f, 0.f, 0.f};
        {
            short8 bfr[4];
            #pragma unroll
            for (int ks = 0; ks < 4; ++ks)
                bfr[ks] = *(const short8*)&Apool[row][ks * 32 + quad * 8];
            #pragma unroll
            for (int mt = 0; mt < 8; ++mt) {
                const unsigned short* wrow = w1t + (size_t)(w * 128 + mt * 16 + row) * DIM;
                #pragma unroll
                for (int ks = 0; ks < 4; ++ks) {
                    short8 afr = *(const short8*)(wrow + ks * 32 + quad * 8);
                    acc[mt] = __builtin_amdgcn_mfma_f32_16x16x32_bf16(afr, bfr[ks], acc[mt], 0, 0, 0);
                }
            }
        }
        // -------- pass 1: bias + ReLU in registers, LN stats --------
        float sum0 = 0.f, ssq0 = 0.f;
        #pragma unroll
        for (int mt = 0; mt < 8; ++mt) {
            const int nb = w * 128 + mt * 16 + quad * 4;
            const float4v bias = *(const float4v*)(b1 + nb);
            #pragma unroll
            for (int r = 0; r < 4; ++r) {
                float v0 = fmaxf(acc[mt][r] + bias[r], 0.f);
                acc[mt][r] = v0;  sum0 += v0;  ssq0 += v0 * v0;
            }
        }
        #pragma unroll
        for (int m = 16; m <= 32; m <<= 1) {       // reduce across the 4 quads
            sum0 += __shfl_xor(sum0, m);  ssq0 += __shfl_xor(ssq0, m);
        }
        if (lane < 16) {
            part[row][w][0] = sum0;  part[row][w][1] = ssq0;
        }
        __syncthreads();             // after this barrier Apool is dead -> Hsm may overwrite
        float mu, rs;
        {
            float S = 0.f, Q = 0.f;
            #pragma unroll
            for (int ww = 0; ww < 4; ++ww) {
                S += part[row][ww][0];
                Q += part[row][ww][1];
            }
            const float invn = 1.f / (float)DFF;
            mu = S * invn;
            float var = Q * invn - mu * mu;
            rs = rsqrtf(var + 1e-5f);
        }
        // -------- pass 2: normalize fp32 regs, pack bf16, single LDS write --------
        #pragma unroll
        for (int mt = 0; mt < 8; ++mt) {
            const int nb = w * 128 + mt * 16 + quad * 4;
            const float4v g4  = *(const float4v*)(gamma + nb);
            const float4v be4 = *(const float4v*)(beta + nb);
            float o[4];
            #pragma unroll
            for (int r = 0; r < 4; ++r) {
                float tg = rs * g4[r];
                o[r] = acc[mt][r] * tg + (be4[r] - mu * tg);
            }
            uint2 p;
            p.x = pk_bf16(o[0], o[1]);
            p.y = pk_bf16(o[2], o[3]);
            *(uint2*)&Hsm[row][nb] = p;
        }
        __syncthreads();

        // -------- GEMM2 (A=Hs [hop][k] LDS, B=w2t [tt][k] global) --------
        {
            float4v acc2 = (float4v){0.f,0.f,0.f,0.f};
            #pragma unroll
            for (int ks = 0; ks < 16; ++ks) {
                const int k0 = ks * 32 + quad * 8;
                short8 bfr = *(const short8*)(w2t + (size_t)(w * 16 + row) * DFF + k0);
                short8 afr = *(const short8*)&Hsm[row][k0];
                acc2 = __builtin_amdgcn_mfma_f32_16x16x32_bf16(afr, bfr, acc2, 0, 0, 0);
            }
            const float bb = b2[w * 16 + row];
            #pragma unroll
            for (int r = 0; r < 4; ++r) {
                int hop = hop0 + quad * 4 + r;
                if (hop < H)
                    out[(size_t)hop * TTW + w * 16 + row] = acc2[r] + bb;
            }
        }
        __syncthreads();             // protect Apool/Hsm reuse by next loop iteration
    }
}

extern "C" void kernel_launch(void* const* d_in, const int* in_sizes, int n_in,
                              void* d_out, int out_size, void* d_ws, size_t ws_size,
                              hipStream_t stream) {
    const float* hf    = (const float*)d_in[0];
    const float* w_q   = (const float*)d_in[1];
    const float* W1    = (const float*)d_in[2];
    const float* b1    = (const float*)d_in[3];
    const float* gamma = (const float*)d_in[4];
    const float* beta  = (const float*)d_in[5];
    const float* W2    = (const float*)d_in[6];
    const float* b2    = (const float*)d_in[7];
    const int* pi      = (const int*)d_in[8];
    const int* stats   = (const int*)d_in[9];
    const int* po      = (const int*)d_in[10];
    float* out         = (float*)d_out;

    int n_hf = in_sizes[0];           // N_NODES*128
    int H    = in_sizes[10];
    int ntiles = (H + TILE_H - 1) / TILE_H;

    // ws layout
    char* ws = (char*)d_ws;
    unsigned short* w1t = (unsigned short*)ws;                       // 128KB
    unsigned short* w2t = (unsigned short*)(ws + 131072);            // 64KB
    unsigned short* hf2 = (unsigned short*)(ws + 196608);            // n_hf*2

    // --- capture-safe queries: deterministic -> same decision every call ---
    int coop_attr = 0, dev = 0;
    hipGetDevice(&dev);
    hipDeviceGetAttribute(&coop_attr, hipDeviceAttributeCooperativeLaunch, dev);
    int maxb = 0;
    hipError_t oe = hipOccupancyMaxActiveBlocksPerMultiprocessor(
        &maxb, fused_t<true>, 256, 0);

    if (coop_attr && oe == hipSuccess && maxb >= 2) {
        int grid = 256 * maxb;            // valid by construction (driver's own count)
        if (grid > 2048) grid = 2048;
        void* args[] = {
            (void*)&hf, (void*)&w_q, (void*)&pi, (void*)&stats, (void*)&po,
            (void*)&W1, (void*)&W2, (void*)&b1, (void*)&gamma, (void*)&beta,
            (void*)&b2, (void*)&hf2, (void*)&w1t, (void*)&w2t, (void*)&out,
            (void*)&H, (void*)&ntiles, (void*)&n_hf
        };
        hipError_t le = hipLaunchCooperativeKernel((const void*)&fused_t<true>,
                                                   dim3(grid), dim3(256),
                                                   args, 0, stream);
        if (le == hipSuccess) return;
        // fall through to the proven 2-kernel path on any launch failure
    }

    const int B_HF = (n_hf + 2047) / 2048;   // 8 elems/thread
    hipLaunchKernelGGL(prep_k, dim3(B_HF + 96), dim3(256), 0, stream,
                       hf, W1, W2, hf2, w1t, w2t, n_hf, B_HF);
    hipLaunchKernelGGL((fused_t<false>), dim3(ntiles), dim3(256), 0, stream,
                       hf, w_q, pi, stats, po, W1, W2, b1, gamma, beta, b2,
                       hf2, w1t, w2t, out, H, ntiles, n_hf);
}

// Round 11
// 207.281 us; speedup vs baseline: 3.2362x; 3.2362x over previous
//
#include <hip/hip_runtime.h>
#include <hip/hip_bf16.h>
#include <math.h>

#define DIM 128
#define DFF 512
#define TTW 64
#define NPI 8
#define NTOK 9
#define TILE_H 32

typedef __attribute__((ext_vector_type(8))) short short8;
typedef __attribute__((ext_vector_type(4))) float float4v;

__device__ __forceinline__ float bf16lo_f32(unsigned u) {
    union { unsigned u; float f; } v; v.u = u << 16;
    return v.f;
}
__device__ __forceinline__ float bf16hi_f32(unsigned u) {
    union { unsigned u; float f; } v; v.u = u & 0xffff0000u;
    return v.f;
}
__device__ __forceinline__ unsigned pk_bf16(float a, float b) {  // -> a | b<<16
    __hip_bfloat162 h = __float22bfloat162_rn(float2{a, b});
    union { __hip_bfloat162 h; unsigned u; } cv; cv.h = h;
    return cv.u;
}

// ============ prep (slim): hf->bf16 (8 elems/thread) + W1/W2 transposes ============
__global__ __launch_bounds__(256)
void prep_k(const float* __restrict__ hf, const float* __restrict__ W1,
            const float* __restrict__ W2,
            unsigned short* __restrict__ hf2, unsigned short* __restrict__ w1t,
            unsigned short* __restrict__ w2t,
            int n_hf, int B_HF)
{
    __shared__ float tile[32][33];
    const int b = blockIdx.x, t = threadIdx.x;
    if (b < B_HF) {
        int i = (b * 256 + t) * 8;
        if (i < n_hf) {
            float4v v0 = *(const float4v*)(hf + i);
            float4v v1 = *(const float4v*)(hf + i + 4);
            uint4 o;
            o.x = pk_bf16(v0[0], v0[1]);
            o.y = pk_bf16(v0[2], v0[3]);
            o.z = pk_bf16(v1[0], v1[1]);
            o.w = pk_bf16(v1[2], v1[3]);
            *(uint4*)(hf2 + i) = o;
        }
    } else if (b < B_HF + 64) {
        const int tb = b - B_HF;            // W1 [128][512] -> w1t bf16 [512][128]
        const int r0 = (tb & 3) * 32, c0 = (tb >> 2) * 32;
        const int ty = t >> 3, tx = t & 7;
        *(float4v*)&tile[ty][tx * 4] = *(const float4v*)(W1 + (r0 + ty) * DFF + c0 + tx * 4);
        __syncthreads();
        uint2 o;
        o.x = pk_bf16(tile[tx * 4 + 0][ty], tile[tx * 4 + 1][ty]);
        o.y = pk_bf16(tile[tx * 4 + 2][ty], tile[tx * 4 + 3][ty]);
        *(uint2*)(w1t + (c0 + ty) * DIM + r0 + tx * 4) = o;
    } else {
        const int tb = b - B_HF - 64;       // W2 [512][64] -> w2t bf16 [64][512]
        const int r0 = (tb & 15) * 32, c0 = (tb >> 4) * 32;
        const int ty = t >> 3, tx = t & 7;
        *(float4v*)&tile[ty][tx * 4] = *(const float4v*)(W2 + (r0 + ty) * TTW + c0 + tx * 4);
        __syncthreads();
        uint2 o;
        o.x = pk_bf16(tile[tx * 4 + 0][ty], tile[tx * 4 + 1][ty]);
        o.y = pk_bf16(tile[tx * 4 + 2][ty], tile[tx * 4 + 3][ty]);
        *(uint2*)(w2t + (c0 + ty) * DFF + r0 + tx * 4) = o;
    }
}

// ===== fused: gather+pool (hoisted loads) -> GEMM1 -> reg-LN -> GEMM2 =====
// __launch_bounds__(256,3): tighter bounds spill the fp32 accumulators
// (R7: WRITE_SIZE 37->214 MB = scratch). Separate Apool/Hsm (R6 config,
// fastest measured: aliasing bought no occupancy, LDS not the limiter).
__global__ __launch_bounds__(256, 3)
void fused_k(const unsigned short* __restrict__ hf2,
             const float* __restrict__ w_q,
             const int* __restrict__ pi,
             const int* __restrict__ stats,
             const int* __restrict__ po,
             const unsigned short* __restrict__ w1t,     // bf16 [512][128]
             const float* __restrict__ b1,
             const float* __restrict__ gamma,
             const float* __restrict__ beta,
             const unsigned short* __restrict__ w2t,     // bf16 [64][512]
             const float* __restrict__ b2,
             float* __restrict__ out,
             int H)
{
    __shared__ __align__(16) unsigned short Apool[TILE_H][DIM + 8];   // 8704 B
    __shared__ __align__(16) unsigned short Hsm[TILE_H][DFF + 8];     // 33280 B
    __shared__ float part[2][16][4][2];                 // [ht][row][wave][sum,ssq]

    const int t    = threadIdx.x;
    const int lane = t & 63;
    const int w    = t >> 6;
    const int row  = lane & 15;
    const int quad = lane >> 4;
    const int hop0 = blockIdx.x * TILE_H;

    // -------- Phase 1: gather + masked attention pooling (32 lanes/hop) --------
    // All 36 token loads issued back-to-back BEFORE any softmax compute so their
    // ~200-900 cyc latency overlaps (fine-grained vmcnt waits at first use).
    {
        const int g = t >> 5, l = t & 31;       // lane l owns dims 4l..4l+3
        const float4v wq4 = *(const float4v*)(w_q + l * 4);

        int idxs[4][NTOK];
        unsigned vm[4];
        #pragma unroll
        for (int it = 0; it < 4; ++it) {
            int hop = hop0 + g + it * 8;
            if (hop >= H) hop = H - 1;          // clamp; out stores are guarded
            int4 p0 = *(const int4*)(pi + hop * NPI);
            int4 p1 = *(const int4*)(pi + hop * NPI + 4);
            int4 s0 = *(const int4*)(stats + hop * NPI);
            int4 s1 = *(const int4*)(stats + hop * NPI + 4);
            idxs[it][0] = p0.x; idxs[it][1] = p0.y;
            idxs[it][2] = p0.z; idxs[it][3] = p0.w;
            idxs[it][4] = p1.x; idxs[it][5] = p1.y;
            idxs[it][6] = p1.z; idxs[it][7] = p1.w;
            idxs[it][8] = po[hop];
            vm[it] = (s0.x != -1 ? 1u   : 0u) | (s0.y != -1 ? 2u   : 0u)
                   | (s0.z != -1 ? 4u   : 0u) | (s0.w != -1 ? 8u   : 0u)
                   | (s1.x != -1 ? 16u  : 0u) | (s1.y != -1 ? 32u  : 0u)
                   | (s1.z != -1 ? 64u  : 0u) | (s1.w != -1 ? 128u : 0u)
                   | 256u;                      // PO always valid
        }
        uint2 tu[4][NTOK];                      // 72 VGPRs; acc not yet live
        #pragma unroll
        for (int it = 0; it < 4; ++it)
            #pragma unroll
            for (int p = 0; p < NTOK; ++p)
                tu[it][p] = *(const uint2*)(hf2 + (size_t)idxs[it][p] * DIM + l * 4);

        #pragma unroll
        for (int it = 0; it < 4; ++it) {
            const int hl = g + it * 8;
            float tok[NTOK][4];
            #pragma unroll
            for (int p = 0; p < NTOK; ++p) {
                tok[p][0] = bf16lo_f32(tu[it][p].x);
                tok[p][1] = bf16hi_f32(tu[it][p].x);
                tok[p][2] = bf16lo_f32(tu[it][p].y);
                tok[p][3] = bf16hi_f32(tu[it][p].y);
            }
            float sc[NTOK];
            #pragma unroll
            for (int p = 0; p < NTOK; ++p)
                sc[p] = tok[p][0]*wq4[0] + tok[p][1]*wq4[1]
                      + tok[p][2]*wq4[2] + tok[p][3]*wq4[3];
            #pragma unroll
            for (int m = 1; m < 32; m <<= 1) {
                #pragma unroll
                for (int p = 0; p < NTOK; ++p) sc[p] += __shfl_xor(sc[p], m);
            }
            const float isd = 0.08838834764831845f;   // 1/sqrt(128)
            float mx = -1e30f;
            #pragma unroll
            for (int p = 0; p < NTOK; ++p) {
                sc[p] = ((vm[it] >> p) & 1u) ? sc[p] * isd : -1e30f;
                mx = fmaxf(mx, sc[p]);
            }
            float se = 0.f;
            #pragma unroll
            for (int p = 0; p < NTOK; ++p) { sc[p] = __expf(sc[p] - mx); se += sc[p]; }
            const float inv = 1.f / se;
            float a0=0.f, a1=0.f, a2=0.f, a3=0.f;
            #pragma unroll
            for (int p = 0; p < NTOK; ++p) {
                float a = sc[p] * inv;
                a0 += a * tok[p][0]; a1 += a * tok[p][1];
                a2 += a * tok[p][2]; a3 += a * tok[p][3];
            }
            uint2 o;
            o.x = pk_bf16(a0, a1);
            o.y = pk_bf16(a2, a3);
            *(uint2*)&Apool[hl][l * 4] = o;
        }
    }
    __syncthreads();

    // -------- GEMM1: A=W1T rows (out-dims), B=Apool^T (hops); all acc live --------
    float4v acc[8][2];
    #pragma unroll
    for (int mt = 0; mt < 8; ++mt) {
        acc[mt][0] = (float4v){0.f, 0.f, 0.f, 0.f};
        acc[mt][1] = (float4v){0.f, 0.f, 0.f, 0.f};
    }
    {
        short8 bfr[2][4];
        #pragma unroll
        for (int ks = 0; ks < 4; ++ks) {
            const int k0 = ks * 32 + quad * 8;
            #pragma unroll
            for (int ht = 0; ht < 2; ++ht)
                bfr[ht][ks] = *(const short8*)&Apool[ht * 16 + row][k0];
        }
        #pragma unroll
        for (int mt = 0; mt < 8; ++mt) {
            const unsigned short* wrow = w1t + (size_t)(w * 128 + mt * 16 + row) * DIM;
            #pragma unroll
            for (int ks = 0; ks < 4; ++ks) {
                short8 afr = *(const short8*)(wrow + ks * 32 + quad * 8);
                acc[mt][0] = __builtin_amdgcn_mfma_f32_16x16x32_bf16(afr, bfr[0][ks], acc[mt][0], 0, 0, 0);
                acc[mt][1] = __builtin_amdgcn_mfma_f32_16x16x32_bf16(afr, bfr[1][ks], acc[mt][1], 0, 0, 0);
            }
        }
    }
    // -------- pass 1: bias + ReLU in registers, LN stats --------
    float sum0 = 0.f, ssq0 = 0.f, sum1 = 0.f, ssq1 = 0.f;
    #pragma unroll
    for (int mt = 0; mt < 8; ++mt) {
        const int nb = w * 128 + mt * 16 + quad * 4;
        const float4v bias = *(const float4v*)(b1 + nb);
        #pragma unroll
        for (int r = 0; r < 4; ++r) {
            float v0 = fmaxf(acc[mt][0][r] + bias[r], 0.f);
            float v1 = fmaxf(acc[mt][1][r] + bias[r], 0.f);
            acc[mt][0][r] = v0;  sum0 += v0;  ssq0 += v0 * v0;
            acc[mt][1][r] = v1;  sum1 += v1;  ssq1 += v1 * v1;
        }
    }
    #pragma unroll
    for (int m = 16; m <= 32; m <<= 1) {       // reduce across the 4 quads
        sum0 += __shfl_xor(sum0, m);  ssq0 += __shfl_xor(ssq0, m);
        sum1 += __shfl_xor(sum1, m);  ssq1 += __shfl_xor(ssq1, m);
    }
    if (lane < 16) {
        part[0][row][w][0] = sum0;  part[0][row][w][1] = ssq0;
        part[1][row][w][0] = sum1;  part[1][row][w][1] = ssq1;
    }
    __syncthreads();
    float mu[2], rs[2];
    #pragma unroll
    for (int ht = 0; ht < 2; ++ht) {
        float S = 0.f, Q = 0.f;
        #pragma unroll
        for (int ww = 0; ww < 4; ++ww) {
            S += part[ht][row][ww][0];
            Q += part[ht][row][ww][1];
        }
        const float invn = 1.f / (float)DFF;
        mu[ht] = S * invn;
        float var = Q * invn - mu[ht] * mu[ht];
        rs[ht] = rsqrtf(var + 1e-5f);
    }
    // -------- pass 2: normalize fp32 regs, pack bf16, single LDS write --------
    #pragma unroll
    for (int mt = 0; mt < 8; ++mt) {
        const int nb = w * 128 + mt * 16 + quad * 4;
        const float4v g4  = *(const float4v*)(gamma + nb);
        const float4v be4 = *(const float4v*)(beta + nb);
        #pragma unroll
        for (int ht = 0; ht < 2; ++ht) {
            float o[4];
            #pragma unroll
            for (int r = 0; r < 4; ++r) {
                float tg = rs[ht] * g4[r];
                o[r] = acc[mt][ht][r] * tg + (be4[r] - mu[ht] * tg);
            }
            uint2 p;
            p.x = pk_bf16(o[0], o[1]);
            p.y = pk_bf16(o[2], o[3]);
            *(uint2*)&Hsm[ht * 16 + row][nb] = p;
        }
    }
    __syncthreads();

    // -------- GEMM2 (A=Hs [hop][k] LDS, B=w2t [tt][k] global) --------
    {
        float4v acc2[2];
        acc2[0] = (float4v){0.f,0.f,0.f,0.f};
        acc2[1] = (float4v){0.f,0.f,0.f,0.f};
        #pragma unroll
        for (int ks = 0; ks < 16; ++ks) {
            const int k0 = ks * 32 + quad * 8;
            short8 bfr = *(const short8*)(w2t + (size_t)(w * 16 + row) * DFF + k0);
            #pragma unroll
            for (int mt = 0; mt < 2; ++mt) {
                short8 afr = *(const short8*)&Hsm[mt * 16 + row][k0];
                acc2[mt] = __builtin_amdgcn_mfma_f32_16x16x32_bf16(
                    afr, bfr, acc2[mt], 0, 0, 0);
            }
        }
        const float bb = b2[w * 16 + row];
        #pragma unroll
        for (int mt = 0; mt < 2; ++mt) {
            #pragma unroll
            for (int r = 0; r < 4; ++r) {
                int hop = hop0 + mt * 16 + quad * 4 + r;
                if (hop < H)
                    out[(size_t)hop * TTW + w * 16 + row] = acc2[mt][r] + bb;
            }
        }
    }
}

extern "C" void kernel_launch(void* const* d_in, const int* in_sizes, int n_in,
                              void* d_out, int out_size, void* d_ws, size_t ws_size,
                              hipStream_t stream) {
    const float* hf    = (const float*)d_in[0];
    const float* w_q   = (const float*)d_in[1];
    const float* W1    = (const float*)d_in[2];
    const float* b1    = (const float*)d_in[3];
    const float* gamma = (const float*)d_in[4];
    const float* beta  = (const float*)d_in[5];
    const float* W2    = (const float*)d_in[6];
    const float* b2    = (const float*)d_in[7];
    const int* pi      = (const int*)d_in[8];
    const int* stats   = (const int*)d_in[9];
    const int* po      = (const int*)d_in[10];
    float* out         = (float*)d_out;

    const int n_hf = in_sizes[0];           // N_NODES*128
    const int H    = in_sizes[10];
    const int ntiles = (H + TILE_H - 1) / TILE_H;

    // ws layout
    char* ws = (char*)d_ws;
    unsigned short* w1t = (unsigned short*)ws;                       // 128KB
    unsigned short* w2t = (unsigned short*)(ws + 131072);            // 64KB
    unsigned short* hf2 = (unsigned short*)(ws + 196608);            // n_hf*2

    const int B_HF = (n_hf + 2047) / 2048;   // 8 elems/thread
    hipLaunchKernelGGL(prep_k, dim3(B_HF + 96), dim3(256), 0, stream,
                       hf, W1, W2, hf2, w1t, w2t, n_hf, B_HF);
    hipLaunchKernelGGL(fused_k, dim3(ntiles), dim3(256), 0, stream,
                       hf2, w_q, pi, stats, po, w1t, b1, gamma, beta, w2t, b2, out, H);
}